// Round 3
// baseline (334.852 us; speedup 1.0000x reference)
//
#include <hip/hip_runtime.h>

#define BATCH 16
#define LQ    1024
#define LK    1024
#define DD    512

typedef unsigned int u32;
typedef unsigned short ushort_t;
typedef short short8 __attribute__((ext_vector_type(8)));
typedef float f32x4 __attribute__((ext_vector_type(4)));
#define AS1 __attribute__((address_space(1)))
#define AS3 __attribute__((address_space(3)))

// ---------------------------------------------------------------------------
// split fp32 -> (bf16 hi by truncation, bf16 lo = trunc(x - hi)) packed pairs
// ---------------------------------------------------------------------------
__device__ __forceinline__ void split2(float x0, float x1, u32& hp, u32& lp) {
    u32 u0 = __float_as_uint(x0), u1 = __float_as_uint(x1);
    hp = __builtin_amdgcn_perm(u1, u0, 0x07060302u);   // (hi0, hi1) as 2 ushorts
    float l0 = x0 - __uint_as_float(u0 & 0xffff0000u);
    float l1 = x1 - __uint_as_float(u1 & 0xffff0000u);
    lp = __builtin_amdgcn_perm(__float_as_uint(l1), __float_as_uint(l0), 0x07060302u);
}

// ---------------------------------------------------------------------------
// Convert Q (linear): 8 elements / thread
// ---------------------------------------------------------------------------
__global__ __launch_bounds__(256) void convert_q(const float* __restrict__ x,
                                                 ushort_t* __restrict__ hi,
                                                 ushort_t* __restrict__ lo) {
    size_t i = ((size_t)blockIdx.x * 256 + threadIdx.x) * 8;
    float4 a = *(const float4*)(x + i);
    float4 b = *(const float4*)(x + i + 4);
    u32 h0, h1, h2, h3, l0, l1, l2, l3;
    split2(a.x, a.y, h0, l0); split2(a.z, a.w, h1, l1);
    split2(b.x, b.y, h2, l2); split2(b.z, b.w, h3, l3);
    uint4 hv; hv.x = h0; hv.y = h1; hv.z = h2; hv.w = h3;
    uint4 lv; lv.x = l0; lv.y = l1; lv.z = l2; lv.w = l3;
    *(uint4*)(hi + i) = hv;
    *(uint4*)(lo + i) = lv;
}

// ---------------------------------------------------------------------------
// Convert V: straight hi/lo [1024 x 512] AND transposed hi/lo [512 x 1024]
// 32x32 tiles via LDS. grid (512/32, 1024/32, BATCH)
// ---------------------------------------------------------------------------
__global__ __launch_bounds__(256) void convert_v(const float* __restrict__ V,
                                                 ushort_t* __restrict__ vhi, ushort_t* __restrict__ vlo,
                                                 ushort_t* __restrict__ vthi, ushort_t* __restrict__ vtlo) {
    __shared__ float tile[32][33];
    const int b = blockIdx.z;
    const int c0 = blockIdx.x * 32;   // d (col) offset
    const int r0 = blockIdx.y * 32;   // kv (row) offset
    const float* Vb = V + (size_t)b * LK * DD;
    const int t = threadIdx.x;
    const int r = t >> 3, c4 = (t & 7) * 4;

    float4 f = *(const float4*)(Vb + (size_t)(r0 + r) * DD + c0 + c4);
    tile[r][c4 + 0] = f.x; tile[r][c4 + 1] = f.y;
    tile[r][c4 + 2] = f.z; tile[r][c4 + 3] = f.w;

    // straight output (no LDS needed)
    {
        u32 h0, h1, l0, l1;
        split2(f.x, f.y, h0, l0); split2(f.z, f.w, h1, l1);
        size_t o = (size_t)b * LK * DD + (size_t)(r0 + r) * DD + c0 + c4;
        uint2 hv; hv.x = h0; hv.y = h1;
        uint2 lv; lv.x = l0; lv.y = l1;
        *(uint2*)(vhi + o) = hv;
        *(uint2*)(vlo + o) = lv;
    }
    __syncthreads();
    // transposed output: Vt[n][k], n = d index, k = kv index
    {
        const int n = t >> 3, k4 = (t & 7) * 4;
        float x0 = tile[k4 + 0][n], x1 = tile[k4 + 1][n];
        float x2 = tile[k4 + 2][n], x3 = tile[k4 + 3][n];
        u32 h0, h1, l0, l1;
        split2(x0, x1, h0, l0); split2(x2, x3, h1, l1);
        size_t o = (size_t)b * DD * LK + (size_t)(c0 + n) * LK + r0 + k4;
        uint2 hv; hv.x = h0; hv.y = h1;
        uint2 lv; lv.x = l0; lv.y = l1;
        *(uint2*)(vthi + o) = hv;
        *(uint2*)(vtlo + o) = lv;
    }
}

// ---------------------------------------------------------------------------
// Split-bf16 MFMA GEMM: C[1024 x NG] = A[1024 x KG] * B[NG x KG]^T  per batch
// 128x128 tile, BK=32, 256 threads = 4 waves, 3 passes: hi*hi + hi*lo + lo*hi.
//
// LDS layout is XOR-swizzled to kill ds_read_b128 bank conflicts:
//   physical 16B-quad = logical quad ^ ((row>>1)&3)
// global_load_lds forces LDS slot = wave_base + lane*16B, so the swizzle is
// applied on the SOURCE side: lane L fetches global quad (L&3)^((L>>3)&3) of
// its row. Fragment reads XOR with ((mf>>1)&3), which is invariant across the
// 16-row fragment step (16*32 stride keeps (row>>1)&3 unchanged).
// ---------------------------------------------------------------------------
template <int KG, int NG>
__global__ __launch_bounds__(256) void gemm_hilo(const ushort_t* __restrict__ Ahi,
                                                 const ushort_t* __restrict__ Alo,
                                                 const ushort_t* __restrict__ Bhi,
                                                 const ushort_t* __restrict__ Blo,
                                                 float* __restrict__ C) {
    __shared__ ushort_t sm[4][128 * 32];   // comps: Ahi, Alo, Bhi, Blo (8 KB each)

    const int b   = blockIdx.z;
    const int bm0 = blockIdx.x * 128;
    const int bn0 = blockIdx.y * 128;
    const int tid = threadIdx.x;
    const int w   = tid >> 6;
    const int lane = tid & 63;

    const size_t Ab = (size_t)b * 1024 * KG + (size_t)bm0 * KG;
    const size_t Bb = (size_t)b * NG * KG + (size_t)bn0 * KG;
    // wave w stages component w (Ahi/Alo/Bhi/Blo)
    const ushort_t* src = (w == 0) ? Ahi + Ab : (w == 1) ? Alo + Ab
                        : (w == 2) ? Bhi + Bb : Blo + Bb;
    // swizzled source quad: lane L covers row (L>>2), physical quad (L&3),
    // which must hold logical quad (L&3) ^ ((L>>3)&3)
    src += (size_t)(lane >> 2) * KG + (size_t)(((lane & 3) ^ ((lane >> 3) & 3)) * 8);
    ushort_t* lbase = &sm[w][0];

    const int wm = (w & 1) * 64, wn = (w >> 1) * 64;
    const int mf = lane & 15, q = lane >> 4;
    const int qsw = (q ^ ((mf >> 1) & 3)) * 8;   // swizzled k-quad offset (ushorts)
    const int aoff = (wm + mf) * 32 + qsw;
    const int boff = (wn + mf) * 32 + qsw;

    f32x4 acc[4][4] = {};

    for (int k0 = 0; k0 < KG; k0 += 32) {
        __syncthreads();   // previous iteration's frag reads done before overwrite
#pragma unroll
        for (int t = 0; t < 8; ++t)
            __builtin_amdgcn_global_load_lds((const AS1 u32*)(src + k0 + (size_t)t * 16 * KG),
                                             (AS3 u32*)(lbase + t * 512), 16, 0, 0);
        __syncthreads();   // staging complete (barrier drains vmcnt)

        short8 ah[4], al[4], bh[4], bl[4];
#pragma unroll
        for (int i = 0; i < 4; ++i) {
            ah[i] = *(const short8*)&sm[0][aoff + i * 512];
            al[i] = *(const short8*)&sm[1][aoff + i * 512];
            bh[i] = *(const short8*)&sm[2][boff + i * 512];
            bl[i] = *(const short8*)&sm[3][boff + i * 512];
        }
#pragma unroll
        for (int i = 0; i < 4; ++i)
#pragma unroll
            for (int j = 0; j < 4; ++j) {
                acc[i][j] = __builtin_amdgcn_mfma_f32_16x16x32_bf16(ah[i], bh[j], acc[i][j], 0, 0, 0);
                acc[i][j] = __builtin_amdgcn_mfma_f32_16x16x32_bf16(ah[i], bl[j], acc[i][j], 0, 0, 0);
                acc[i][j] = __builtin_amdgcn_mfma_f32_16x16x32_bf16(al[i], bh[j], acc[i][j], 0, 0, 0);
            }
    }

    // epilogue: C/D layout col = lane&15, row = q*4 + reg  [m89-verified]
    float* Cb = C + (size_t)b * 1024 * NG + (size_t)bm0 * NG + bn0;
#pragma unroll
    for (int i = 0; i < 4; ++i)
#pragma unroll
        for (int j = 0; j < 4; ++j)
#pragma unroll
            for (int r = 0; r < 4; ++r)
                Cb[(size_t)(wm + i * 16 + q * 4 + r) * NG + wn + j * 16 + mf] = acc[i][j][r];
}

// ---------------------------------------------------------------------------
// Row softmax in place + pack P into bf16 hi/lo for the PV gemm
// ---------------------------------------------------------------------------
__global__ __launch_bounds__(256) void softmax_conv(float* __restrict__ S,
                                                    ushort_t* __restrict__ Phi,
                                                    ushort_t* __restrict__ Plo) {
    const size_t row = blockIdx.x;
    float* p = S + row * LK;
    const int t = threadIdx.x;

    float4 v = *(float4*)(p + (t << 2));
    float m = fmaxf(fmaxf(v.x, v.y), fmaxf(v.z, v.w));
#pragma unroll
    for (int off = 1; off < 64; off <<= 1)
        m = fmaxf(m, __shfl_xor(m, off, 64));

    __shared__ float redm[4];
    __shared__ float reds[4];
    const int wave = t >> 6, lane = t & 63;
    if (lane == 0) redm[wave] = m;
    __syncthreads();
    m = fmaxf(fmaxf(redm[0], redm[1]), fmaxf(redm[2], redm[3]));

    v.x = __expf(v.x - m); v.y = __expf(v.y - m);
    v.z = __expf(v.z - m); v.w = __expf(v.w - m);
    float s = (v.x + v.y) + (v.z + v.w);
#pragma unroll
    for (int off = 1; off < 64; off <<= 1)
        s += __shfl_xor(s, off, 64);
    if (lane == 0) reds[wave] = s;
    __syncthreads();
    s = (reds[0] + reds[1]) + (reds[2] + reds[3]);

    const float inv = 1.0f / s;
    v.x *= inv; v.y *= inv; v.z *= inv; v.w *= inv;
    *(float4*)(p + (t << 2)) = v;

    u32 h0, h1, l0, l1;
    split2(v.x, v.y, h0, l0); split2(v.z, v.w, h1, l1);
    uint2 hv; hv.x = h0; hv.y = h1;
    uint2 lv; lv.x = l0; lv.y = l1;
    *(uint2*)(Phi + row * LK + (t << 2)) = hv;
    *(uint2*)(Plo + row * LK + (t << 2)) = lv;
}

// ===========================================================================
// Fallback fp32 path (round-1 kernels) — used only if ws_size is too small
// ===========================================================================
constexpr int BM = 64, BN = 64, BK = 16, PAD = 4;

__global__ __launch_bounds__(256) void gemm_qvt(const float* __restrict__ Q,
                                                const float* __restrict__ V,
                                                float* __restrict__ S) {
    __shared__ __align__(16) float sA[BK][BM + PAD];
    __shared__ __align__(16) float sB[BK][BN + PAD];
    const int b = blockIdx.z;
    const float* Qb = Q + (size_t)b * LQ * DD + (size_t)blockIdx.x * BM * DD;
    const float* Vb = V + (size_t)b * LK * DD + (size_t)blockIdx.y * BN * DD;
    float*       Sb = S + (size_t)b * LQ * LK;
    const int tid = threadIdx.x;
    const int tx = tid & 15, ty = tid >> 4;
    const int lr = tid >> 2, lc = (tid & 3) << 2;
    float acc[4][4] = {};
    for (int k0 = 0; k0 < DD; k0 += BK) {
        float4 qa = *(const float4*)(Qb + (size_t)lr * DD + k0 + lc);
        float4 va = *(const float4*)(Vb + (size_t)lr * DD + k0 + lc);
        __syncthreads();
        sA[lc + 0][lr] = qa.x; sA[lc + 1][lr] = qa.y; sA[lc + 2][lr] = qa.z; sA[lc + 3][lr] = qa.w;
        sB[lc + 0][lr] = va.x; sB[lc + 1][lr] = va.y; sB[lc + 2][lr] = va.z; sB[lc + 3][lr] = va.w;
        __syncthreads();
#pragma unroll
        for (int k = 0; k < BK; ++k) {
            float4 a4 = *(const float4*)&sA[k][ty << 2];
            float4 b4 = *(const float4*)&sB[k][tx << 2];
            float a[4] = {a4.x, a4.y, a4.z, a4.w};
            float bb[4] = {b4.x, b4.y, b4.z, b4.w};
#pragma unroll
            for (int i = 0; i < 4; ++i)
#pragma unroll
                for (int j = 0; j < 4; ++j) acc[i][j] = fmaf(a[i], bb[j], acc[i][j]);
        }
    }
    const int r0 = blockIdx.x * BM + (ty << 2), c0 = blockIdx.y * BN + (tx << 2);
#pragma unroll
    for (int i = 0; i < 4; ++i) {
        float4 o = {acc[i][0], acc[i][1], acc[i][2], acc[i][3]};
        *(float4*)(Sb + (size_t)(r0 + i) * LK + c0) = o;
    }
}

__global__ __launch_bounds__(256) void softmax_rows(float* __restrict__ S) {
    float* p = S + (size_t)blockIdx.x * LK;
    const int t = threadIdx.x;
    float4 v = *(float4*)(p + (t << 2));
    float m = fmaxf(fmaxf(v.x, v.y), fmaxf(v.z, v.w));
#pragma unroll
    for (int off = 1; off < 64; off <<= 1) m = fmaxf(m, __shfl_xor(m, off, 64));
    __shared__ float redm[4]; __shared__ float reds[4];
    const int wave = t >> 6, lane = t & 63;
    if (lane == 0) redm[wave] = m;
    __syncthreads();
    m = fmaxf(fmaxf(redm[0], redm[1]), fmaxf(redm[2], redm[3]));
    v.x = __expf(v.x - m); v.y = __expf(v.y - m); v.z = __expf(v.z - m); v.w = __expf(v.w - m);
    float s = (v.x + v.y) + (v.z + v.w);
#pragma unroll
    for (int off = 1; off < 64; off <<= 1) s += __shfl_xor(s, off, 64);
    if (lane == 0) reds[wave] = s;
    __syncthreads();
    s = (reds[0] + reds[1]) + (reds[2] + reds[3]);
    const float inv = 1.0f / s;
    v.x *= inv; v.y *= inv; v.z *= inv; v.w *= inv;
    *(float4*)(p + (t << 2)) = v;
}

__global__ __launch_bounds__(256) void gemm_pv(const float* __restrict__ P,
                                               const float* __restrict__ V,
                                               float* __restrict__ C) {
    __shared__ __align__(16) float sA[BK][BM + PAD];
    __shared__ __align__(16) float sB[BK][BN + PAD];
    const int b = blockIdx.z;
    const float* Pb = P + (size_t)b * LQ * LK + (size_t)blockIdx.x * BM * LK;
    const float* Vb = V + (size_t)b * LK * DD;
    float*       Cb = C + (size_t)b * LQ * DD;
    const int tid = threadIdx.x;
    const int tx = tid & 15, ty = tid >> 4;
    const int lr = tid >> 2, lc = (tid & 3) << 2;
    const int bkr = tid >> 4, bcg = (tid & 15) << 2;
    const int n0 = blockIdx.y * BN;
    float acc[4][4] = {};
    for (int k0 = 0; k0 < LK; k0 += BK) {
        float4 pa = *(const float4*)(Pb + (size_t)lr * LK + k0 + lc);
        float4 vb = *(const float4*)(Vb + (size_t)(k0 + bkr) * DD + n0 + bcg);
        __syncthreads();
        sA[lc + 0][lr] = pa.x; sA[lc + 1][lr] = pa.y; sA[lc + 2][lr] = pa.z; sA[lc + 3][lr] = pa.w;
        *(float4*)&sB[bkr][bcg] = vb;
        __syncthreads();
#pragma unroll
        for (int k = 0; k < BK; ++k) {
            float4 a4 = *(const float4*)&sA[k][ty << 2];
            float4 b4 = *(const float4*)&sB[k][tx << 2];
            float a[4] = {a4.x, a4.y, a4.z, a4.w};
            float bb[4] = {b4.x, b4.y, b4.z, b4.w};
#pragma unroll
            for (int i = 0; i < 4; ++i)
#pragma unroll
                for (int j = 0; j < 4; ++j) acc[i][j] = fmaf(a[i], bb[j], acc[i][j]);
        }
    }
    const int r0 = blockIdx.x * BM + (ty << 2), c0 = n0 + (tx << 2);
#pragma unroll
    for (int i = 0; i < 4; ++i) {
        float4 o = {acc[i][0], acc[i][1], acc[i][2], acc[i][3]};
        *(float4*)(Cb + (size_t)(r0 + i) * DD + c0) = o;
    }
}

// ---------------------------------------------------------------------------
extern "C" void kernel_launch(void* const* d_in, const int* in_sizes, int n_in,
                              void* d_out, int out_size, void* d_ws, size_t ws_size,
                              hipStream_t stream) {
    const float* Q = (const float*)d_in[0];
    const float* V = (const float*)d_in[1];

    float* ctx  = (float*)d_out;                       // [16,1024,512]
    float* attn = ctx + (size_t)BATCH * LQ * DD;       // [16,1024,1024]

    const size_t NQ = (size_t)BATCH * LQ * DD;   // 8,388,608
    const size_t NP = (size_t)BATCH * LQ * LK;   // 16,777,216
    const size_t needed = (6 * NQ + 2 * NP) * sizeof(ushort_t);  // 160 MiB

    if (ws_size >= needed) {
        ushort_t* w = (ushort_t*)d_ws;
        ushort_t* Qhi = w;            ushort_t* Qlo = w + NQ;
        ushort_t* Vhi = w + 2 * NQ;   ushort_t* Vlo = w + 3 * NQ;
        ushort_t* Vthi = w + 4 * NQ;  ushort_t* Vtlo = w + 5 * NQ;
        ushort_t* Phi = w + 6 * NQ;   ushort_t* Plo = w + 6 * NQ + NP;

        convert_q<<<dim3(NQ / (256 * 8)), 256, 0, stream>>>(Q, Qhi, Qlo);
        convert_v<<<dim3(DD / 32, LK / 32, BATCH), 256, 0, stream>>>(V, Vhi, Vlo, Vthi, Vtlo);
        // S = Q @ V^T  (A: [1024,512] k-contig, B: [1024,512] k-contig)
        gemm_hilo<DD, LK><<<dim3(8, 8, BATCH), 256, 0, stream>>>(Qhi, Qlo, Vhi, Vlo, attn);
        // softmax in place + pack P
        softmax_conv<<<dim3(BATCH * LQ), 256, 0, stream>>>(attn, Phi, Plo);
        // context = P @ V  (A: P [1024,1024] k-contig, B: Vt [512,1024] k-contig)
        gemm_hilo<LK, DD><<<dim3(8, 4, BATCH), 256, 0, stream>>>(Phi, Plo, Vthi, Vtlo, ctx);
    } else {
        // fallback: fp32 path (correct, slower)
        gemm_qvt<<<dim3(LQ / BM, LK / BN, BATCH), 256, 0, stream>>>(Q, V, attn);
        softmax_rows<<<dim3(BATCH * LQ), 256, 0, stream>>>(attn);
        gemm_pv<<<dim3(LQ / BM, DD / BN, BATCH), 256, 0, stream>>>(attn, V, ctx);
    }
}

// Round 4
// 267.962 us; speedup vs baseline: 1.2496x; 1.2496x over previous
//
#include <hip/hip_runtime.h>

#define BATCH 16
#define LQ    1024
#define LK    1024
#define DD    512

typedef unsigned int u32;
typedef short short8 __attribute__((ext_vector_type(8)));
typedef float f32x4 __attribute__((ext_vector_type(4)));
#define AS1 __attribute__((address_space(1)))
#define AS3 __attribute__((address_space(3)))

// ---------------------------------------------------------------------------
// split fp32 pair -> packed bf16 hi (truncation) and bf16 lo (= x - hi)
// ---------------------------------------------------------------------------
__device__ __forceinline__ void split2(float x0, float x1, u32& hp, u32& lp) {
    u32 u0 = __float_as_uint(x0), u1 = __float_as_uint(x1);
    hp = __builtin_amdgcn_perm(u1, u0, 0x07060302u);   // (bf16(x0), bf16(x1))
    float l0 = x0 - __uint_as_float(u0 & 0xffff0000u);
    float l1 = x1 - __uint_as_float(u1 & 0xffff0000u);
    lp = __builtin_amdgcn_perm(__float_as_uint(l1), __float_as_uint(l0), 0x07060302u);
}

// 8 logical-k floats (f0 = k 8q..8q+3, f1 = k 8q+4..8q+7) -> hi/lo MFMA frags
__device__ __forceinline__ void mk_frags(f32x4 f0, f32x4 f1, short8& h, short8& l) {
    union { u32 u[4]; short8 s; } H, L;
    split2(f0[0], f0[1], H.u[0], L.u[0]);
    split2(f0[2], f0[3], H.u[1], L.u[1]);
    split2(f1[0], f1[1], H.u[2], L.u[2]);
    split2(f1[2], f1[3], H.u[3], L.u[3]);
    h = H.s; l = L.s;
}

// ---------------------------------------------------------------------------
// V [LK x DD] -> Vt [DD x LK], fp32, per batch. grid (DD/32, LK/32, BATCH)
// ---------------------------------------------------------------------------
__global__ __launch_bounds__(256) void transpose_v(const float* __restrict__ V,
                                                   float* __restrict__ Vt) {
    __shared__ float tile[32][33];
    const int b = blockIdx.z;
    const int c0 = blockIdx.x * 32;   // d
    const int r0 = blockIdx.y * 32;   // kv
    const int t = threadIdx.x;
    const int r = t >> 3, c4 = (t & 7) * 4;
    const float* Vb = V + (size_t)b * LK * DD;
    float4 f = *(const float4*)(Vb + (size_t)(r0 + r) * DD + c0 + c4);
    tile[r][c4 + 0] = f.x; tile[r][c4 + 1] = f.y;
    tile[r][c4 + 2] = f.z; tile[r][c4 + 3] = f.w;
    __syncthreads();
    const int n = t >> 3, k4 = (t & 7) * 4;
    float4 o = {tile[k4 + 0][n], tile[k4 + 1][n], tile[k4 + 2][n], tile[k4 + 3][n]};
    *(float4*)(Vt + (size_t)b * DD * LK + (size_t)(c0 + n) * LK + r0 + k4) = o;
}

// ---------------------------------------------------------------------------
// Split-bf16 MFMA GEMM, fp32 operands staged directly:
//   C[1024 x NG] = A[1024 x KG] * B[NG x KG]^T   per batch
// 128x128 tile, BK=32, 4 waves, double-buffered LDS (2 x 32 KB), one barrier
// per K-step with prefetch issued before compute (loads get the whole compute
// phase in flight before the pre-barrier vmcnt drain).
//
// LDS swizzle (128 B rows = 8 x 16B chunks): phys chunk = logical ^ (row&7).
// global_load_lds lane L covers row (L>>3), phys chunk (L&7), so the source
// fetches logical chunk (L&7)^(L>>3) -> coalescing kept (128 B clusters).
// Frag reads: logical chunks 2q,2q+1 at row mf -> phys (2q)^e,(2q+1)^e with
// e = mf&7; each 16-lane phase spreads 2 lanes/chunk = free 2-way.
// hi/lo split done in-register after ds_read (same LDS bytes as bf16 hi+lo).
// ---------------------------------------------------------------------------
template <int KG, int NG>
__global__ __launch_bounds__(256) void gemm_f32split(const float* __restrict__ A,
                                                     const float* __restrict__ B,
                                                     float* __restrict__ C) {
    __shared__ float sm[2][2][128 * 32];   // [buf][operand][row*32 + float] = 64 KB

    const int b   = blockIdx.z;
    const int bm0 = blockIdx.x * 128;
    const int bn0 = blockIdx.y * 128;
    const int tid = threadIdx.x;
    const int w   = tid >> 6;
    const int lane = tid & 63;

    // staging: waves 0,1 -> A rows [w*64, +64); waves 2,3 -> B rows [(w-2)*64, +64)
    const int op   = w >> 1;
    const int woff = (w & 1) * 64;
    const float* gsrc = (op == 0)
        ? A + (size_t)b * 1024 * KG + (size_t)(bm0 + woff) * KG
        : B + (size_t)b * NG * KG   + (size_t)(bn0 + woff) * KG;
    gsrc += (size_t)(lane >> 3) * KG + (size_t)(((lane & 7) ^ (lane >> 3)) * 4);

    const int mf = lane & 15, q = lane >> 4;
    const int e  = mf & 7;
    const int c0 = ((2 * q) ^ e) * 4;       // float offset of logical chunk 2q
    const int c1 = ((2 * q + 1) ^ e) * 4;   // float offset of logical chunk 2q+1
    const int wm = (w & 1) * 64, wn = (w >> 1) * 64;

    f32x4 acc[4][4] = {};

    auto stage = [&](int pb, int k) {
#pragma unroll
        for (int t = 0; t < 8; ++t)
            __builtin_amdgcn_global_load_lds((const AS1 u32*)(gsrc + k + (size_t)t * 8 * KG),
                                             (AS3 u32*)(&sm[pb][op][(woff + t * 8) * 32]),
                                             16, 0, 0);
    };

    stage(0, 0);
    int p = 0;
    for (int k0 = 0; k0 < KG; k0 += 32) {
        __syncthreads();                 // drains prefetch into sm[p]; protects sm[p^1]
        if (k0 + 32 < KG) stage(p ^ 1, k0 + 32);

        const float* As = &sm[p][0][0];
        const float* Bs = &sm[p][1][0];
        short8 ah[4], al[4], bh[4], bl[4];
#pragma unroll
        for (int i = 0; i < 4; ++i) {
            const int ra = (wm + mf + i * 16) * 32;
            f32x4 f0 = *(const f32x4*)&As[ra + c0];
            f32x4 f1 = *(const f32x4*)&As[ra + c1];
            mk_frags(f0, f1, ah[i], al[i]);
            const int rb = (wn + mf + i * 16) * 32;
            f32x4 g0 = *(const f32x4*)&Bs[rb + c0];
            f32x4 g1 = *(const f32x4*)&Bs[rb + c1];
            mk_frags(g0, g1, bh[i], bl[i]);
        }
#pragma unroll
        for (int i = 0; i < 4; ++i)
#pragma unroll
            for (int j = 0; j < 4; ++j) {
                acc[i][j] = __builtin_amdgcn_mfma_f32_16x16x32_bf16(ah[i], bh[j], acc[i][j], 0, 0, 0);
                acc[i][j] = __builtin_amdgcn_mfma_f32_16x16x32_bf16(ah[i], bl[j], acc[i][j], 0, 0, 0);
                acc[i][j] = __builtin_amdgcn_mfma_f32_16x16x32_bf16(al[i], bh[j], acc[i][j], 0, 0, 0);
            }
        p ^= 1;
    }

    // epilogue: C/D layout col = lane&15, row = q*4 + reg  [m89-verified]
    float* Cb = C + (size_t)b * 1024 * NG + (size_t)bm0 * NG + bn0;
#pragma unroll
    for (int i = 0; i < 4; ++i)
#pragma unroll
        for (int j = 0; j < 4; ++j)
#pragma unroll
            for (int r = 0; r < 4; ++r)
                Cb[(size_t)(wm + i * 16 + q * 4 + r) * NG + wn + j * 16 + mf] = acc[i][j][r];
}

// ---------------------------------------------------------------------------
// Row softmax in place: 16384 rows of 1024. One block (256 thr) per row.
// ---------------------------------------------------------------------------
__global__ __launch_bounds__(256) void softmax_rows(float* __restrict__ S) {
    float* p = S + (size_t)blockIdx.x * LK;
    const int t = threadIdx.x;
    float4 v = *(float4*)(p + (t << 2));
    float m = fmaxf(fmaxf(v.x, v.y), fmaxf(v.z, v.w));
#pragma unroll
    for (int off = 1; off < 64; off <<= 1) m = fmaxf(m, __shfl_xor(m, off, 64));
    __shared__ float redm[4]; __shared__ float reds[4];
    const int wave = t >> 6, lane = t & 63;
    if (lane == 0) redm[wave] = m;
    __syncthreads();
    m = fmaxf(fmaxf(redm[0], redm[1]), fmaxf(redm[2], redm[3]));
    v.x = __expf(v.x - m); v.y = __expf(v.y - m);
    v.z = __expf(v.z - m); v.w = __expf(v.w - m);
    float s = (v.x + v.y) + (v.z + v.w);
#pragma unroll
    for (int off = 1; off < 64; off <<= 1) s += __shfl_xor(s, off, 64);
    if (lane == 0) reds[wave] = s;
    __syncthreads();
    s = (reds[0] + reds[1]) + (reds[2] + reds[3]);
    const float inv = 1.0f / s;
    v.x *= inv; v.y *= inv; v.z *= inv; v.w *= inv;
    *(float4*)(p + (t << 2)) = v;
}

// ===========================================================================
// Fallback fp32 path — used only if ws_size is too small for Vt (33.6 MB)
// ===========================================================================
constexpr int BM = 64, BN = 64, BK = 16, PAD = 4;

__global__ __launch_bounds__(256) void gemm_qvt(const float* __restrict__ Q,
                                                const float* __restrict__ V,
                                                float* __restrict__ S) {
    __shared__ __align__(16) float sA[BK][BM + PAD];
    __shared__ __align__(16) float sB[BK][BN + PAD];
    const int b = blockIdx.z;
    const float* Qb = Q + (size_t)b * LQ * DD + (size_t)blockIdx.x * BM * DD;
    const float* Vb = V + (size_t)b * LK * DD + (size_t)blockIdx.y * BN * DD;
    float*       Sb = S + (size_t)b * LQ * LK;
    const int tid = threadIdx.x;
    const int tx = tid & 15, ty = tid >> 4;
    const int lr = tid >> 2, lc = (tid & 3) << 2;
    float acc[4][4] = {};
    for (int k0 = 0; k0 < DD; k0 += BK) {
        float4 qa = *(const float4*)(Qb + (size_t)lr * DD + k0 + lc);
        float4 va = *(const float4*)(Vb + (size_t)lr * DD + k0 + lc);
        __syncthreads();
        sA[lc + 0][lr] = qa.x; sA[lc + 1][lr] = qa.y; sA[lc + 2][lr] = qa.z; sA[lc + 3][lr] = qa.w;
        sB[lc + 0][lr] = va.x; sB[lc + 1][lr] = va.y; sB[lc + 2][lr] = va.z; sB[lc + 3][lr] = va.w;
        __syncthreads();
#pragma unroll
        for (int k = 0; k < BK; ++k) {
            float4 a4 = *(const float4*)&sA[k][ty << 2];
            float4 b4 = *(const float4*)&sB[k][tx << 2];
            float a[4] = {a4.x, a4.y, a4.z, a4.w};
            float bb[4] = {b4.x, b4.y, b4.z, b4.w};
#pragma unroll
            for (int i = 0; i < 4; ++i)
#pragma unroll
                for (int j = 0; j < 4; ++j) acc[i][j] = fmaf(a[i], bb[j], acc[i][j]);
        }
    }
    const int r0 = blockIdx.x * BM + (ty << 2), c0 = blockIdx.y * BN + (tx << 2);
#pragma unroll
    for (int i = 0; i < 4; ++i) {
        float4 o = {acc[i][0], acc[i][1], acc[i][2], acc[i][3]};
        *(float4*)(Sb + (size_t)(r0 + i) * LK + c0) = o;
    }
}

__global__ __launch_bounds__(256) void gemm_pv(const float* __restrict__ P,
                                               const float* __restrict__ V,
                                               float* __restrict__ C) {
    __shared__ __align__(16) float sA[BK][BM + PAD];
    __shared__ __align__(16) float sB[BK][BN + PAD];
    const int b = blockIdx.z;
    const float* Pb = P + (size_t)b * LQ * LK + (size_t)blockIdx.x * BM * LK;
    const float* Vb = V + (size_t)b * LK * DD;
    float*       Cb = C + (size_t)b * LQ * DD;
    const int tid = threadIdx.x;
    const int tx = tid & 15, ty = tid >> 4;
    const int lr = tid >> 2, lc = (tid & 3) << 2;
    const int bkr = tid >> 4, bcg = (tid & 15) << 2;
    const int n0 = blockIdx.y * BN;
    float acc[4][4] = {};
    for (int k0 = 0; k0 < LK; k0 += BK) {
        float4 pa = *(const float4*)(Pb + (size_t)lr * LK + k0 + lc);
        float4 vb = *(const float4*)(Vb + (size_t)(k0 + bkr) * DD + n0 + bcg);
        __syncthreads();
        sA[lc + 0][lr] = pa.x; sA[lc + 1][lr] = pa.y; sA[lc + 2][lr] = pa.z; sA[lc + 3][lr] = pa.w;
        *(float4*)&sB[bkr][bcg] = vb;
        __syncthreads();
#pragma unroll
        for (int k = 0; k < BK; ++k) {
            float4 a4 = *(const float4*)&sA[k][ty << 2];
            float4 b4 = *(const float4*)&sB[k][tx << 2];
            float a[4] = {a4.x, a4.y, a4.z, a4.w};
            float bb[4] = {b4.x, b4.y, b4.z, b4.w};
#pragma unroll
            for (int i = 0; i < 4; ++i)
#pragma unroll
                for (int j = 0; j < 4; ++j) acc[i][j] = fmaf(a[i], bb[j], acc[i][j]);
        }
    }
    const int r0 = blockIdx.x * BM + (ty << 2), c0 = n0 + (tx << 2);
#pragma unroll
    for (int i = 0; i < 4; ++i) {
        float4 o = {acc[i][0], acc[i][1], acc[i][2], acc[i][3]};
        *(float4*)(Cb + (size_t)(r0 + i) * DD + c0) = o;
    }
}

// ---------------------------------------------------------------------------
extern "C" void kernel_launch(void* const* d_in, const int* in_sizes, int n_in,
                              void* d_out, int out_size, void* d_ws, size_t ws_size,
                              hipStream_t stream) {
    const float* Q = (const float*)d_in[0];
    const float* V = (const float*)d_in[1];

    float* ctx  = (float*)d_out;                       // [16,1024,512]
    float* attn = ctx + (size_t)BATCH * LQ * DD;       // [16,1024,1024]

    const size_t vt_elems = (size_t)BATCH * DD * LK;   // 8.4M floats = 33.6 MB

    if (ws_size >= vt_elems * sizeof(float)) {
        float* Vt = (float*)d_ws;
        transpose_v<<<dim3(DD / 32, LK / 32, BATCH), 256, 0, stream>>>(V, Vt);
        // S = Q @ V^T : A = Q [1024,512], B = V [1024,512] (both k-contig)
        gemm_f32split<DD, LK><<<dim3(8, 8, BATCH), 256, 0, stream>>>(Q, V, attn);
        softmax_rows<<<dim3(BATCH * LQ), 256, 0, stream>>>(attn);
        // ctx = P @ V : A = P [1024,1024], B = Vt [512,1024] (both k-contig)
        gemm_f32split<LK, DD><<<dim3(8, 4, BATCH), 256, 0, stream>>>(attn, Vt, ctx);
    } else {
        gemm_qvt<<<dim3(LQ / BM, LK / BN, BATCH), 256, 0, stream>>>(Q, V, attn);
        softmax_rows<<<dim3(BATCH * LQ), 256, 0, stream>>>(attn);
        gemm_pv<<<dim3(LQ / BM, DD / BN, BATCH), 256, 0, stream>>>(attn, V, ctx);
    }
}